// Round 2
// baseline (822.354 us; speedup 1.0000x reference)
//
#include <hip/hip_runtime.h>

#define DIM 64
#define EPS 1e-8f

// ---------------------------------------------------------------------------
// Pipeline (CSR-based, no float atomics):
//   K1a/K1b/K1c : exclusive scan of degree -> offsets[] (+cursor copy)
//   K2          : h = x @ fc_w^T + fc_b
//   K3          : counting sort: csr_col grouped by row (1 int atomic/edge)
//   K4 (fused)  : per node: acc = deg*h[i] + sum h[csr_col];  alpha/beta/gamma
//                 recomputed from x (cheaper than 154MB round-trip);
//                 out = (beta*acc + gamma)/(alpha + beta*deg + EPS)
// Algebraic fold: agg[i] = outdeg(i)*h[i] + sum_{e:row=i} h[col_e], and the
// given `degree` IS the out-degree -> the h[row] half of msg is free.
// ---------------------------------------------------------------------------

// ---- K1a: per-256-block local exclusive scan of int(degree), block sums ----
__global__ __launch_bounds__(256) void scan1_kernel(
    const float* __restrict__ degree, int* __restrict__ off,
    int* __restrict__ bsum, int n)
{
  __shared__ int s[256];
  const int t = threadIdx.x;
  const int i = blockIdx.x * 256 + t;
  const int v = (i < n) ? (int)(degree[i] + 0.5f) : 0;
  s[t] = v;
  __syncthreads();
  for (int st = 1; st < 256; st <<= 1) {
    int a = (t >= st) ? s[t - st] : 0;
    __syncthreads();
    s[t] += a;
    __syncthreads();
  }
  if (i < n) off[i] = s[t] - v;          // local exclusive
  if (t == 255) bsum[blockIdx.x] = s[t]; // block total
}

// ---- K1b: scan block sums (single block, 512 threads, chunked) -------------
__global__ __launch_bounds__(512) void scan2_kernel(
    const int* __restrict__ bsum, int* __restrict__ bpre,
    int* __restrict__ off, int nb, int ch, int n)
{
  __shared__ int s[512];
  const int t = threadIdx.x;
  const int base = t * ch;
  int local = 0;
  for (int q = 0; q < ch; ++q) {
    const int j = base + q;
    if (j < nb) local += bsum[j];
  }
  s[t] = local;
  __syncthreads();
  for (int st = 1; st < 512; st <<= 1) {
    int a = (t >= st) ? s[t - st] : 0;
    __syncthreads();
    s[t] += a;
    __syncthreads();
  }
  int run = s[t] - local;                // exclusive prefix of this chunk
  for (int q = 0; q < ch; ++q) {
    const int j = base + q;
    if (j < nb) { bpre[j] = run; run += bsum[j]; }
  }
  if (t == 511) off[n] = s[511];         // grand total (= E)
}

// ---- K1c: add block prefixes; produce final offsets + cursor copy ----------
__global__ __launch_bounds__(256) void scan3_kernel(
    int* __restrict__ off, int* __restrict__ cur,
    const int* __restrict__ bpre, int n)
{
  const int i = blockIdx.x * 256 + threadIdx.x;
  if (i < n) {
    const int o = off[i] + bpre[blockIdx.x];
    off[i] = o;
    cur[i] = o;
  }
}

// ---- K2: h = x @ fc_w^T + fc_b  (wave-per-node, XOR-swizzled LDS) ----------
__global__ __launch_bounds__(256) void node_h_kernel(
    const float* __restrict__ x, const float* __restrict__ fc_w,
    const float* __restrict__ fc_b, float* __restrict__ h, int n)
{
  __shared__ float w_lds[DIM * DIM];
  __shared__ float b_lds[DIM];
  const int t = threadIdx.x;
  for (int i = t; i < DIM * DIM; i += 256) {
    const int d = i >> 6, k = i & 63;
    w_lds[(k << 6) | (d ^ k)] = fc_w[i];   // transposed + swizzled: conflict-free
  }
  if (t < DIM) b_lds[t] = fc_b[t];
  __syncthreads();

  const int lane = t & 63;
  const int wid = (blockIdx.x << 2) + (t >> 6);
  const int nwaves = gridDim.x << 2;
  for (int node = wid; node < n; node += nwaves) {
    const float xv = x[(size_t)node * DIM + lane];   // coalesced 256B/wave
    float acc = b_lds[lane];
#pragma unroll
    for (int k = 0; k < DIM; ++k) {
      acc = fmaf(__shfl(xv, k, 64), w_lds[(k << 6) | (lane ^ k)], acc);
    }
    h[(size_t)node * DIM + lane] = acc;
  }
}

// ---- K3: counting sort of cols by row (1 int atomic per edge) --------------
__global__ __launch_bounds__(256) void sort_kernel(
    const int* __restrict__ ei, int* __restrict__ cur,
    int* __restrict__ csr, int E)
{
  const int tid = blockIdx.x * 256 + threadIdx.x;
  const int stride = gridDim.x * 256;
  for (int e = tid; e < E; e += stride) {
    const int r = ei[e];
    const int c = ei[E + e];
    const int p = atomicAdd(&cur[r], 1);
    csr[p] = c;               // random 4B scatter, absorbed by L2 (6.4MB)
  }
}

// ---- K4: fused gather + epilogue -------------------------------------------
// Wave-per-node. acc = deg*h[i] + sum over csr neighbors of h[col] (register
// accumulate, no atomics). alpha/beta/gamma matvecs use one interleaved
// [k][(d^k)<<2] float4 LDS tile (64KB): one ds_read_b128 feeds 3 FMAs/k-step.
// 512 thr/block, 64KB LDS -> 2 blocks/CU = 4 waves/SIMD.
__global__ __launch_bounds__(512, 4) void gather_out_kernel(
    const float* __restrict__ x, const float* __restrict__ h,
    const int* __restrict__ off, const int* __restrict__ csr,
    const float* __restrict__ degree,
    const float* __restrict__ dir_w, const float* __restrict__ dir_b,
    const float* __restrict__ neu_w, const float* __restrict__ neu_b,
    const float* __restrict__ rob_w, const float* __restrict__ rob_b,
    float* __restrict__ out, int n)
{
  __shared__ float w_lds[DIM * DIM * 4];
  __shared__ float b_lds[3 * DIM];
  const int t = threadIdx.x;
  for (int i = t; i < DIM * DIM; i += 512) {
    const int d = i >> 6, k = i & 63;
    const int s = (k << 8) | ((d ^ k) << 2);   // float idx; staging 2-way max
    w_lds[s + 0] = dir_w[i];
    w_lds[s + 1] = neu_w[i];
    w_lds[s + 2] = rob_w[i];
  }
  if (t < DIM) {
    b_lds[t] = dir_b[t];
    b_lds[64 + t] = neu_b[t];
    b_lds[128 + t] = rob_b[t];
  }
  __syncthreads();

  const int lane = t & 63;
  const int wid = (blockIdx.x << 3) + (t >> 6);
  const int nwaves = gridDim.x << 3;
  for (int node = wid; node < n; node += nwaves) {
    const size_t rowo = (size_t)node * DIM + lane;
    const float xv = x[rowo];
    const float hv = h[rowo];
    const float deg = degree[node];
    const int o0 = off[node];
    const int o1 = off[node + 1];

    // ---- neighbor gather (register accumulate; unroll-4 for MLP) ----
    float acc = deg * hv;
    int j = o0;
    for (; j + 4 <= o1; j += 4) {
      const int c0 = csr[j + 0], c1 = csr[j + 1];
      const int c2 = csr[j + 2], c3 = csr[j + 3];
      const float v0 = h[((size_t)c0 << 6) | lane];
      const float v1 = h[((size_t)c1 << 6) | lane];
      const float v2 = h[((size_t)c2 << 6) | lane];
      const float v3 = h[((size_t)c3 << 6) | lane];
      acc += v0; acc += v1; acc += v2; acc += v3;
    }
    for (; j < o1; ++j) {
      acc += h[((size_t)csr[j] << 6) | lane];
    }

    // ---- alpha/beta/gamma matvecs (shfl-broadcast x, b128 LDS reads) ----
    float a = b_lds[lane];
    float b = b_lds[64 + lane];
    float g = b_lds[128 + lane];
#pragma unroll
    for (int k = 0; k < DIM; ++k) {
      const float xk = __shfl(xv, k, 64);
      const float4 w = *(const float4*)&w_lds[(k << 8) | ((lane ^ k) << 2)];
      a = fmaf(xk, w.x, a);
      b = fmaf(xk, w.y, b);
      g = fmaf(xk, w.z, g);
    }
    a = fmaxf(a, 0.f);
    b = fmaxf(b, 0.f);
    out[rowo] = fmaf(b, acc, g) / (fmaf(b, deg, a) + EPS);
  }
}

extern "C" void kernel_launch(void* const* d_in, const int* in_sizes, int n_in,
                              void* d_out, int out_size, void* d_ws, size_t ws_size,
                              hipStream_t stream) {
  const float* x      = (const float*)d_in[0];
  const int*   ei     = (const int*)  d_in[1];
  const float* degree = (const float*)d_in[2];
  const float* fc_w   = (const float*)d_in[3];
  const float* fc_b   = (const float*)d_in[4];
  const float* dir_w  = (const float*)d_in[5];
  const float* dir_b  = (const float*)d_in[6];
  const float* neu_w  = (const float*)d_in[7];
  const float* neu_b  = (const float*)d_in[8];
  const float* rob_w  = (const float*)d_in[9];
  const float* rob_b  = (const float*)d_in[10];
  float* out = (float*)d_out;

  const int n = in_sizes[0] / DIM;
  const int E = in_sizes[1] / 2;
  const int NB = (n + 255) / 256;         // scan blocks
  const int CH = (NB + 511) / 512;        // chunk per thread in scan2

  // workspace layout (all 4B types): h | csr | off | cur | bsum | bpre
  float* h    = (float*)d_ws;
  int*   csr  = (int*)(h + (size_t)n * DIM);
  int*   off  = csr + E;
  int*   cur  = off + (n + 1);
  int*   bsum = cur + n;
  int*   bpre = bsum + NB;

  hipLaunchKernelGGL(scan1_kernel, dim3(NB), dim3(256), 0, stream,
                     degree, off, bsum, n);
  hipLaunchKernelGGL(scan2_kernel, dim3(1), dim3(512), 0, stream,
                     bsum, bpre, off, NB, CH, n);
  hipLaunchKernelGGL(scan3_kernel, dim3(NB), dim3(256), 0, stream,
                     off, cur, bpre, n);
  hipLaunchKernelGGL(node_h_kernel, dim3(1024), dim3(256), 0, stream,
                     x, fc_w, fc_b, h, n);
  hipLaunchKernelGGL(sort_kernel, dim3(2048), dim3(256), 0, stream,
                     ei, cur, csr, E);
  hipLaunchKernelGGL(gather_out_kernel, dim3(512), dim3(512), 0, stream,
                     x, h, off, csr, degree,
                     dir_w, dir_b, neu_w, neu_b, rob_w, rob_b, out, n);
}